// Round 5
// baseline (124.402 us; speedup 1.0000x reference)
//
#include <hip/hip_runtime.h>
#include <math.h>

// Problem constants
#define T_STEPS 50
#define NS      2048
#define IND     16
#define HID     128
#define GATES   512
#define RR      8
#define KN      32
#define EPSV    1e-10f

// LSTM MFMA tiling: 512 blocks x 4 rows x 4 waves -> 2 independent blocks/CU
// (separate barrier groups; breaks the round-4 phase lock).
#define LROWS   4
#define APAD    152     // f16 row stride: 304B = 16B-aligned, 2-way banks only
#define LTH     256     // 4 waves; wave w owns gate cols [32w, 32w+32)

typedef _Float16 f16x8 __attribute__((ext_vector_type(8)));
typedef _Float16 f16x4 __attribute__((ext_vector_type(4)));
typedef float    f32x4 __attribute__((ext_vector_type(4)));

__device__ __forceinline__ float sigm(float x)  { return 1.0f / (1.0f + __expf(-x)); }
__device__ __forceinline__ float tanhf_(float x){ return 1.0f - 2.0f / (1.0f + __expf(2.0f * x)); }

// ---------------------------------------------------------------------------
// LSTM via MFMA f16. 4 real rows placed at M-rows {0,4,8,12} of the 16-row
// tile -> every lane's C reg r=0 is a real cell (no shfl redistribution).
// K split: x (K=16) via 16x16x16 MFMA, h (K=128) via 4x 16x16x32 frags.
// Weights register-resident (keep-alive asm). One barrier per step.
// ---------------------------------------------------------------------------
__global__ __launch_bounds__(LTH, 2) void lstm_mfma_kernel(
    const float* __restrict__ x,     // (T, NS, IND)
    const float* __restrict__ W_ih,  // (GATES, IND)
    const float* __restrict__ W_hh,  // (GATES, HID)
    const float* __restrict__ b_ih,  // (GATES)
    const float* __restrict__ b_hh,  // (GATES)
    float* __restrict__ se)          // (NS, HID) out
{
    __shared__ __align__(16) _Float16 sA[2][16][APAD];            // 9.5 KB
    __shared__ __align__(16) _Float16 sX[T_STEPS][LROWS * IND];   // 6.4 KB

    const int tid    = threadIdx.x;
    const int w      = tid >> 6;       // wave 0..3
    const int l      = tid & 63;
    const int lane16 = l & 15;
    const int lgrp   = l >> 4;         // 0..3
    const int n0     = blockIdx.x * LROWS;

    // ---- prologue: W -> f16 fragments in registers (static all 50 steps)
    // tile s in {0,1}: gate col gi = 128*gg + 32*w + 16*s + lane16
    // Bh[gg][s][kf]: k = kf*32 + lgrp*8 + j (h part, K=128)
    // Bx[gg][s]:     k = lgrp*4 + j        (x part, K=16)
    f16x8 Bh[4][2][4];
    f16x4 Bx[4][2];
    float bias[4][2];
#pragma unroll
    for (int gg = 0; gg < 4; ++gg) {
#pragma unroll
        for (int s = 0; s < 2; ++s) {
            const int gi = 128 * gg + 32 * w + 16 * s + lane16;
            bias[gg][s] = b_ih[gi] + b_hh[gi];
            f16x4 vx;
#pragma unroll
            for (int j = 0; j < 4; ++j)
                vx[j] = (_Float16)W_ih[gi * IND + lgrp * 4 + j];
            Bx[gg][s] = vx;
#pragma unroll
            for (int kf = 0; kf < 4; ++kf) {
                f16x8 v;
                const float* p = W_hh + gi * HID + kf * 32 + lgrp * 8;
#pragma unroll
                for (int j = 0; j < 8; ++j) v[j] = (_Float16)p[j];
                Bh[gg][s][kf] = v;
            }
        }
    }
    // Opaque to the optimizer: cannot rematerialize -> stays resident.
#pragma unroll
    for (int gg = 0; gg < 4; ++gg)
#pragma unroll
        for (int s = 0; s < 2; ++s) {
            asm volatile("" : "+v"(Bx[gg][s]));
#pragma unroll
            for (int kf = 0; kf < 4; ++kf)
                asm volatile("" : "+v"(Bh[gg][s][kf]));
        }

    // zero both sA buffers (dummy M-rows + h0 = 0)
    for (int i = tid; i < 2 * 16 * APAD; i += LTH)
        (&sA[0][0][0])[i] = (_Float16)0.0f;

    // stage ALL x for this block's 4 rows, f16 (coalesced, once)
    for (int i = tid; i < T_STEPS * LROWS * IND; i += LTH) {
        const int t = i >> 6, e = i & 63;
        sX[t][e] = (_Float16)x[((size_t)t * NS + n0) * IND + e];
    }
    __syncthreads();
    // x_0: wave w writes row w (M-row 4w), cols 0..15
    if (l < 16) sA[0][4 * w][l] = sX[0][16 * w + l];
    __syncthreads();

    // lane owns cells (row lgrp, col 32w+lane16) and (row lgrp, col 32w+16+lane16)
    float c0 = 0.f, c1 = 0.f, h0 = 0.f, h1 = 0.f;

    for (int step = 0; step < T_STEPS; ++step) {
        const int cur = step & 1, nxt = cur ^ 1;

        // A fragments (shared by both tiles): row = lane16
        f16x4 Ax = *(const f16x4*)&sA[cur][lane16][lgrp * 4];
        f16x8 Ah[4];
#pragma unroll
        for (int kf = 0; kf < 4; ++kf)
            Ah[kf] = *(const f16x8*)&sA[cur][lane16][16 + kf * 32 + lgrp * 8];

        _Float16 xv = (_Float16)0.0f;
        if (step + 1 < T_STEPS && l < 16) xv = sX[step + 1][16 * w + l];

        // ---- tile 0
        {
            f32x4 az[4];
#pragma unroll
            for (int gg = 0; gg < 4; ++gg) {
                az[gg] = (f32x4){bias[gg][0], bias[gg][0], bias[gg][0], bias[gg][0]};
                az[gg] = __builtin_amdgcn_mfma_f32_16x16x16f16(Ax, Bx[gg][0], az[gg], 0, 0, 0);
            }
#pragma unroll
            for (int kf = 0; kf < 4; ++kf) {
#pragma unroll
                for (int gg = 0; gg < 4; ++gg)
                    az[gg] = __builtin_amdgcn_mfma_f32_16x16x32_f16(Ah[kf], Bh[gg][0][kf], az[gg], 0, 0, 0);
            }
            c0 = sigm(az[1][0]) * c0 + sigm(az[0][0]) * tanhf_(az[2][0]);
            h0 = sigm(az[3][0]) * tanhf_(c0);
        }
        // ---- tile 1
        {
            f32x4 az[4];
#pragma unroll
            for (int gg = 0; gg < 4; ++gg) {
                az[gg] = (f32x4){bias[gg][1], bias[gg][1], bias[gg][1], bias[gg][1]};
                az[gg] = __builtin_amdgcn_mfma_f32_16x16x16f16(Ax, Bx[gg][1], az[gg], 0, 0, 0);
            }
#pragma unroll
            for (int kf = 0; kf < 4; ++kf) {
#pragma unroll
                for (int gg = 0; gg < 4; ++gg)
                    az[gg] = __builtin_amdgcn_mfma_f32_16x16x32_f16(Ah[kf], Bh[gg][1][kf], az[gg], 0, 0, 0);
            }
            c1 = sigm(az[1][0]) * c1 + sigm(az[0][0]) * tanhf_(az[2][0]);
            h1 = sigm(az[3][0]) * tanhf_(c1);
        }

        // write h_{t+1} (row lgrp -> M-row 4*lgrp) and x_{t+1}; one barrier
        if (step + 1 < T_STEPS) {
            sA[nxt][4 * lgrp][16 + 32 * w + lane16]      = (_Float16)h0;
            sA[nxt][4 * lgrp][16 + 32 * w + 16 + lane16] = (_Float16)h1;
            if (l < 16) sA[nxt][4 * w][l] = xv;
        }
        __syncthreads();
    }

    se[(n0 + lgrp) * HID + 32 * w + lane16]      = h0;
    se[(n0 + lgrp) * HID + 32 * w + 16 + lane16] = h1;
}

// ---------------------------------------------------------------------------
// Kernel 2: per-(r,n) neighbor attention (f16 LDS staging). Unchanged.
// ---------------------------------------------------------------------------
__global__ __launch_bounds__(256) void attn_kernel(
    const float* __restrict__ se,
    const int*   __restrict__ neighbors,
    const float* __restrict__ rel_num,
    const float* __restrict__ w_att,
    const float* __restrict__ b_att,
    const float* __restrict__ w_rel,
    const float* __restrict__ b_rel,
    float* __restrict__ rel_rep,
    float* __restrict__ rscore)
{
    __shared__ _Float16 snb[4][KN][HID + 8];
    __shared__ int      sidx[4][KN];

    const int wid  = threadIdx.x >> 6;
    const int lane = threadIdx.x & 63;
    const int pair = blockIdx.x * 4 + wid;   // = r*NS + n
    const int r    = pair >> 11;
    const int n    = pair & (NS - 1);

    if (lane < KN) sidx[wid][lane] = neighbors[(size_t)pair * KN + lane];
    __syncthreads();

    const float4* se4 = (const float4*)se;
#pragma unroll
    for (int m = 0; m < (KN * HID / 4) / 64; ++m) {
        int flat = m * 64 + lane;
        int row  = flat >> 5;
        int c4   = flat & 31;
        int idx  = sidx[wid][row];
        float4 v = make_float4(0.f, 0.f, 0.f, 0.f);
        if (idx != 0) v = se4[(size_t)(idx - 1) * (HID / 4) + c4];
        f16x4 hv = { (_Float16)v.x, (_Float16)v.y, (_Float16)v.z, (_Float16)v.w };
        *((f16x4*)&snb[wid][row][c4 * 4]) = hv;
    }
    __syncthreads();

    float p2 = se[n * HID + lane] * w_att[HID + lane]
             + se[n * HID + 64 + lane] * w_att[HID + 64 + lane];
#pragma unroll
    for (int d = 32; d > 0; d >>= 1) p2 += __shfl_xor(p2, d);

    const int k    = lane & 31;
    const int half = lane >> 5;
    float ps = 0.f;
#pragma unroll
    for (int h4 = 0; h4 < 16; ++h4) {
        f16x4  v  = *(const f16x4*)&snb[wid][k][half * 64 + h4 * 4];
        float4 wv = *(const float4*)&w_att[half * 64 + h4 * 4];
        ps += (float)v[0] * wv.x + (float)v[1] * wv.y
            + (float)v[2] * wv.z + (float)v[3] * wv.w;
    }
    ps += __shfl_down(ps, 32);

    float s = ps + p2 + w_att[2 * HID + r] + b_att[0];
    float mx = s;
#pragma unroll
    for (int d = 16; d > 0; d >>= 1) mx = fmaxf(mx, __shfl_xor(mx, d, 32));
    float e  = __expf(s - mx);
    float sm = e;
#pragma unroll
    for (int d = 16; d > 0; d >>= 1) sm += __shfl_xor(sm, d, 32);
    float att = e / sm;

    const float inv = 1.0f / (rel_num[pair] + EPSV);
    float a0 = 0.f, a1 = 0.f;
#pragma unroll
    for (int kk = 0; kk < KN; ++kk) {
        float av = __shfl(att, kk);
        a0 += av * (float)snb[wid][kk][lane];
        a1 += av * (float)snb[wid][kk][64 + lane];
    }
    a0 *= inv;
    a1 *= inv;
    rel_rep[(size_t)pair * HID + lane]      = a0;
    rel_rep[(size_t)pair * HID + 64 + lane] = a1;

    float pr = a0 * w_rel[lane] + a1 * w_rel[64 + lane];
#pragma unroll
    for (int d = 32; d > 0; d >>= 1) pr += __shfl_xor(pr, d);
    if (lane == 0) rscore[pair] = pr + w_rel[HID + r] + b_rel[0];
}

// ---------------------------------------------------------------------------
// Kernel 3: per-row combine. Unchanged.
// ---------------------------------------------------------------------------
__global__ __launch_bounds__(256) void combine_kernel(
    const float* __restrict__ se,
    const float* __restrict__ rel_rep,
    const float* __restrict__ rscore,
    const float* __restrict__ w_fc1,
    const float* __restrict__ b_fc1,
    float* __restrict__ out)
{
    const int wid  = threadIdx.x >> 6;
    const int lane = threadIdx.x & 63;
    const int n    = blockIdx.x * 4 + wid;

    float rs[RR];
    float mx = -1e30f;
#pragma unroll
    for (int r = 0; r < RR; ++r) {
        rs[r] = rscore[r * NS + n];
        mx = fmaxf(mx, rs[r]);
    }
    float sm = 0.f;
#pragma unroll
    for (int r = 0; r < RR; ++r) {
        rs[r] = __expf(rs[r] - mx);
        sm += rs[r];
    }
    const float invs = 1.0f / (sm * (float)RR);

    float a0 = 0.f, a1 = 0.f;
#pragma unroll
    for (int r = 0; r < RR; ++r) {
        a0 += rs[r] * rel_rep[((size_t)r * NS + n) * HID + lane];
        a1 += rs[r] * rel_rep[((size_t)r * NS + n) * HID + 64 + lane];
    }
    a0 = a0 * invs + se[n * HID + lane];
    a1 = a1 * invs + se[n * HID + 64 + lane];

    float p = a0 * w_fc1[lane] + a1 * w_fc1[64 + lane];
#pragma unroll
    for (int d = 32; d > 0; d >>= 1) p += __shfl_xor(p, d);
    if (lane == 0) out[n] = p + b_fc1[0];
}

// ---------------------------------------------------------------------------
extern "C" void kernel_launch(void* const* d_in, const int* in_sizes, int n_in,
                              void* d_out, int out_size, void* d_ws, size_t ws_size,
                              hipStream_t stream) {
    const float* x      = (const float*)d_in[0];
    const int*   nbrs   = (const int*)  d_in[1];
    const float* relnum = (const float*)d_in[2];
    const float* W_ih   = (const float*)d_in[3];
    const float* W_hh   = (const float*)d_in[4];
    const float* b_ih   = (const float*)d_in[5];
    const float* b_hh   = (const float*)d_in[6];
    const float* w_att  = (const float*)d_in[7];
    const float* b_att  = (const float*)d_in[8];
    const float* w_rel  = (const float*)d_in[9];
    const float* b_rel  = (const float*)d_in[10];
    const float* w_fc1  = (const float*)d_in[11];
    const float* b_fc1  = (const float*)d_in[12];
    float* out = (float*)d_out;

    float* se      = (float*)d_ws;
    float* rel_rep = se + (size_t)NS * HID;
    float* rscore  = rel_rep + (size_t)RR * NS * HID;

    hipLaunchKernelGGL(lstm_mfma_kernel, dim3(NS / LROWS), dim3(LTH), 0, stream,
                       x, W_ih, W_hh, b_ih, b_hh, se);
    hipLaunchKernelGGL(attn_kernel, dim3(RR * NS / 4), dim3(256), 0, stream,
                       se, nbrs, relnum, w_att, b_att, w_rel, b_rel, rel_rep, rscore);
    hipLaunchKernelGGL(combine_kernel, dim3(NS / 4), dim3(256), 0, stream,
                       se, rel_rep, rscore, w_fc1, b_fc1, out);
}

// Round 6
// 81.733 us; speedup vs baseline: 1.5221x; 1.5221x over previous
//
#include <hip/hip_runtime.h>
#include <math.h>

// Problem constants
#define T_STEPS 50
#define NS      2048
#define IND     16
#define HID     128
#define GATES   512
#define RR      8
#define KN      32
#define EPSV    1e-10f

// LSTM MFMA tiling (round-4 proven structure): 256 blocks x 8 rows, 8 waves.
#define LROWS   8
#define APAD    168     // padded f16 row stride of the A tile
#define LTH     512     // 8 waves; wave w owns gate cols [16w,16w+16) per group

typedef _Float16 f16x8 __attribute__((ext_vector_type(8)));
typedef _Float16 f16x4 __attribute__((ext_vector_type(4)));
typedef float    f32x4 __attribute__((ext_vector_type(4)));

// Fast activations: raw v_rcp_f32 (1 ULP) instead of the ~8-inst precise-div
// sequence the compiler emits for 1.0f/x without fast-math.
__device__ __forceinline__ float rcp_(float x)  { return __builtin_amdgcn_rcpf(x); }
__device__ __forceinline__ float sigm(float x)  { return rcp_(1.0f + __expf(-x)); }
__device__ __forceinline__ float tanhf_(float x){ return 1.0f - 2.0f * rcp_(1.0f + __expf(2.0f * x)); }

// ---------------------------------------------------------------------------
// LSTM via MFMA f16. 8 real rows at EVEN M-rows {0,2,...,14} of the 16-row
// tile: C-regs r=0 and r=2 of every lane are real cells -> all 64 lanes do
// 2 cells with ZERO cross-lane redistribution (round 4 needed 8 shfl+8 sel).
// Weights register-resident (keep-alive asm); x LDS-staged; double-buffered
// sA; one barrier per step.
// ---------------------------------------------------------------------------
__global__ __launch_bounds__(LTH, 2) void lstm_mfma_kernel(
    const float* __restrict__ x,     // (T, NS, IND)
    const float* __restrict__ W_ih,  // (GATES, IND)
    const float* __restrict__ W_hh,  // (GATES, HID)
    const float* __restrict__ b_ih,  // (GATES)
    const float* __restrict__ b_hh,  // (GATES)
    float* __restrict__ se)          // (NS, HID) out
{
    __shared__ __align__(16) _Float16 sA[2][16][APAD];           // 10.75 KB
    __shared__ __align__(16) _Float16 sX[T_STEPS][LROWS * IND];  // 12.8 KB

    const int tid    = threadIdx.x;
    const int w      = tid >> 6;       // wave 0..7
    const int l      = tid & 63;
    const int lane16 = l & 15;
    const int lgrp   = l >> 4;         // 0..3 (MFMA fragment row group)
    const int n0     = blockIdx.x * LROWS;

    // ---- prologue: W -> f16 B-fragments in registers (static all 50 steps)
    // B[gg][kf]: gate col gi = 128*gg + 16*w + lane16 ; k = kf*32 + lgrp*8 + j
    // K layout: [x(16) | h(128) | pad(16)]
    f16x8 B[4][5];
    float bias[4];
#pragma unroll
    for (int gg = 0; gg < 4; ++gg) {
        const int gi = 128 * gg + 16 * w + lane16;
        bias[gg] = b_ih[gi] + b_hh[gi];
#pragma unroll
        for (int kf = 0; kf < 5; ++kf) {
            const int k0 = kf * 32 + lgrp * 8;
            f16x8 v;
            if (k0 < 16) {                       // x part -> W_ih
                const float* p = W_ih + gi * IND + k0;
#pragma unroll
                for (int j = 0; j < 8; ++j) v[j] = (_Float16)p[j];
            } else if (k0 >= 144) {              // zero pad
#pragma unroll
                for (int j = 0; j < 8; ++j) v[j] = (_Float16)0.0f;
            } else {                             // h part -> W_hh
                const float* p = W_hh + gi * HID + (k0 - 16);
#pragma unroll
                for (int j = 0; j < 8; ++j) v[j] = (_Float16)p[j];
            }
            B[gg][kf] = v;
        }
    }
    // Opaque to the optimizer: B cannot be rematerialized -> stays resident.
#pragma unroll
    for (int gg = 0; gg < 4; ++gg)
#pragma unroll
        for (int kf = 0; kf < 5; ++kf)
            asm volatile("" : "+v"(B[gg][kf]));

    // zero both sA buffers (odd M-rows + K-pad stay zero forever)
    for (int i = tid; i < 2 * 16 * APAD; i += LTH)
        (&sA[0][0][0])[i] = (_Float16)0.0f;

    // stage ALL x for this block's 8 rows, f16 (coalesced, once)
    for (int i = tid; i < T_STEPS * LROWS * IND; i += LTH) {
        const int t = i >> 7, e = i & 127;
        sX[t][e] = (_Float16)x[((size_t)t * NS + n0) * IND + e];
    }
    __syncthreads();
    // x_0: real row r -> M-row 2r
    if (tid < LROWS * IND) sA[0][2 * (tid >> 4)][tid & 15] = sX[0][tid];
    __syncthreads();

    // lane owns cells (real rows 2*lgrp, 2*lgrp+1; col 16w+lane16)
    // = C-regs r=0 (M-row 4*lgrp) and r=2 (M-row 4*lgrp+2)
    float c0 = 0.f, c1 = 0.f, h0 = 0.f, h1 = 0.f;

    for (int step = 0; step < T_STEPS; ++step) {
        const int cur = step & 1, nxt = cur ^ 1;

        // A fragments: lane -> M-row = lane16 (odd rows read zeros)
        f16x8 A[5];
#pragma unroll
        for (int kf = 0; kf < 5; ++kf)
            A[kf] = *(const f16x8*)&sA[cur][lane16][kf * 32 + lgrp * 8];

        _Float16 xv = (_Float16)0.0f;
        if (step + 1 < T_STEPS && tid < LROWS * IND) xv = sX[step + 1][tid];

        f32x4 zi = {bias[0], bias[0], bias[0], bias[0]};
        f32x4 zf = {bias[1], bias[1], bias[1], bias[1]};
        f32x4 zg = {bias[2], bias[2], bias[2], bias[2]};
        f32x4 zo = {bias[3], bias[3], bias[3], bias[3]};
#pragma unroll
        for (int kf = 0; kf < 5; ++kf) {
            zi = __builtin_amdgcn_mfma_f32_16x16x32_f16(A[kf], B[0][kf], zi, 0, 0, 0);
            zf = __builtin_amdgcn_mfma_f32_16x16x32_f16(A[kf], B[1][kf], zf, 0, 0, 0);
            zg = __builtin_amdgcn_mfma_f32_16x16x32_f16(A[kf], B[2][kf], zg, 0, 0, 0);
            zo = __builtin_amdgcn_mfma_f32_16x16x32_f16(A[kf], B[3][kf], zo, 0, 0, 0);
        }

        // cell update on C-regs 0 and 2 (both real; no cross-lane ops)
        c0 = sigm(zf[0]) * c0 + sigm(zi[0]) * tanhf_(zg[0]);
        h0 = sigm(zo[0]) * tanhf_(c0);
        c1 = sigm(zf[2]) * c1 + sigm(zi[2]) * tanhf_(zg[2]);
        h1 = sigm(zo[2]) * tanhf_(c1);

        // write x_{t+1}, h_{t+1} into the other buffer; one barrier per step
        if (step + 1 < T_STEPS) {
            if (tid < LROWS * IND) sA[nxt][2 * (tid >> 4)][tid & 15] = xv;
            sA[nxt][4 * lgrp][16 + 16 * w + lane16]     = (_Float16)h0;
            sA[nxt][4 * lgrp + 2][16 + 16 * w + lane16] = (_Float16)h1;
        }
        __syncthreads();
    }

    se[(n0 + 2 * lgrp) * HID + 16 * w + lane16]     = h0;
    se[(n0 + 2 * lgrp + 1) * HID + 16 * w + lane16] = h1;
}

// ---------------------------------------------------------------------------
// Kernel 2: per-(r,n) neighbor attention (f16 LDS staging). Unchanged.
// ---------------------------------------------------------------------------
__global__ __launch_bounds__(256) void attn_kernel(
    const float* __restrict__ se,
    const int*   __restrict__ neighbors,
    const float* __restrict__ rel_num,
    const float* __restrict__ w_att,
    const float* __restrict__ b_att,
    const float* __restrict__ w_rel,
    const float* __restrict__ b_rel,
    float* __restrict__ rel_rep,
    float* __restrict__ rscore)
{
    __shared__ _Float16 snb[4][KN][HID + 8];
    __shared__ int      sidx[4][KN];

    const int wid  = threadIdx.x >> 6;
    const int lane = threadIdx.x & 63;
    const int pair = blockIdx.x * 4 + wid;   // = r*NS + n
    const int r    = pair >> 11;
    const int n    = pair & (NS - 1);

    if (lane < KN) sidx[wid][lane] = neighbors[(size_t)pair * KN + lane];
    __syncthreads();

    const float4* se4 = (const float4*)se;
#pragma unroll
    for (int m = 0; m < (KN * HID / 4) / 64; ++m) {
        int flat = m * 64 + lane;
        int row  = flat >> 5;
        int c4   = flat & 31;
        int idx  = sidx[wid][row];
        float4 v = make_float4(0.f, 0.f, 0.f, 0.f);
        if (idx != 0) v = se4[(size_t)(idx - 1) * (HID / 4) + c4];
        f16x4 hv = { (_Float16)v.x, (_Float16)v.y, (_Float16)v.z, (_Float16)v.w };
        *((f16x4*)&snb[wid][row][c4 * 4]) = hv;
    }
    __syncthreads();

    float p2 = se[n * HID + lane] * w_att[HID + lane]
             + se[n * HID + 64 + lane] * w_att[HID + 64 + lane];
#pragma unroll
    for (int d = 32; d > 0; d >>= 1) p2 += __shfl_xor(p2, d);

    const int k    = lane & 31;
    const int half = lane >> 5;
    float ps = 0.f;
#pragma unroll
    for (int h4 = 0; h4 < 16; ++h4) {
        f16x4  v  = *(const f16x4*)&snb[wid][k][half * 64 + h4 * 4];
        float4 wv = *(const float4*)&w_att[half * 64 + h4 * 4];
        ps += (float)v[0] * wv.x + (float)v[1] * wv.y
            + (float)v[2] * wv.z + (float)v[3] * wv.w;
    }
    ps += __shfl_down(ps, 32);

    float s = ps + p2 + w_att[2 * HID + r] + b_att[0];
    float mx = s;
#pragma unroll
    for (int d = 16; d > 0; d >>= 1) mx = fmaxf(mx, __shfl_xor(mx, d, 32));
    float e  = __expf(s - mx);
    float sm = e;
#pragma unroll
    for (int d = 16; d > 0; d >>= 1) sm += __shfl_xor(sm, d, 32);
    float att = e / sm;

    const float inv = 1.0f / (rel_num[pair] + EPSV);
    float a0 = 0.f, a1 = 0.f;
#pragma unroll
    for (int kk = 0; kk < KN; ++kk) {
        float av = __shfl(att, kk);
        a0 += av * (float)snb[wid][kk][lane];
        a1 += av * (float)snb[wid][kk][64 + lane];
    }
    a0 *= inv;
    a1 *= inv;
    rel_rep[(size_t)pair * HID + lane]      = a0;
    rel_rep[(size_t)pair * HID + 64 + lane] = a1;

    float pr = a0 * w_rel[lane] + a1 * w_rel[64 + lane];
#pragma unroll
    for (int d = 32; d > 0; d >>= 1) pr += __shfl_xor(pr, d);
    if (lane == 0) rscore[pair] = pr + w_rel[HID + r] + b_rel[0];
}

// ---------------------------------------------------------------------------
// Kernel 3: per-row combine. Unchanged.
// ---------------------------------------------------------------------------
__global__ __launch_bounds__(256) void combine_kernel(
    const float* __restrict__ se,
    const float* __restrict__ rel_rep,
    const float* __restrict__ rscore,
    const float* __restrict__ w_fc1,
    const float* __restrict__ b_fc1,
    float* __restrict__ out)
{
    const int wid  = threadIdx.x >> 6;
    const int lane = threadIdx.x & 63;
    const int n    = blockIdx.x * 4 + wid;

    float rs[RR];
    float mx = -1e30f;
#pragma unroll
    for (int r = 0; r < RR; ++r) {
        rs[r] = rscore[r * NS + n];
        mx = fmaxf(mx, rs[r]);
    }
    float sm = 0.f;
#pragma unroll
    for (int r = 0; r < RR; ++r) {
        rs[r] = __expf(rs[r] - mx);
        sm += rs[r];
    }
    const float invs = 1.0f / (sm * (float)RR);

    float a0 = 0.f, a1 = 0.f;
#pragma unroll
    for (int r = 0; r < RR; ++r) {
        a0 += rs[r] * rel_rep[((size_t)r * NS + n) * HID + lane];
        a1 += rs[r] * rel_rep[((size_t)r * NS + n) * HID + 64 + lane];
    }
    a0 = a0 * invs + se[n * HID + lane];
    a1 = a1 * invs + se[n * HID + 64 + lane];

    float p = a0 * w_fc1[lane] + a1 * w_fc1[64 + lane];
#pragma unroll
    for (int d = 32; d > 0; d >>= 1) p += __shfl_xor(p, d);
    if (lane == 0) out[n] = p + b_fc1[0];
}

// ---------------------------------------------------------------------------
extern "C" void kernel_launch(void* const* d_in, const int* in_sizes, int n_in,
                              void* d_out, int out_size, void* d_ws, size_t ws_size,
                              hipStream_t stream) {
    const float* x      = (const float*)d_in[0];
    const int*   nbrs   = (const int*)  d_in[1];
    const float* relnum = (const float*)d_in[2];
    const float* W_ih   = (const float*)d_in[3];
    const float* W_hh   = (const float*)d_in[4];
    const float* b_ih   = (const float*)d_in[5];
    const float* b_hh   = (const float*)d_in[6];
    const float* w_att  = (const float*)d_in[7];
    const float* b_att  = (const float*)d_in[8];
    const float* w_rel  = (const float*)d_in[9];
    const float* b_rel  = (const float*)d_in[10];
    const float* w_fc1  = (const float*)d_in[11];
    const float* b_fc1  = (const float*)d_in[12];
    float* out = (float*)d_out;

    float* se      = (float*)d_ws;
    float* rel_rep = se + (size_t)NS * HID;
    float* rscore  = rel_rep + (size_t)RR * NS * HID;

    hipLaunchKernelGGL(lstm_mfma_kernel, dim3(NS / LROWS), dim3(LTH), 0, stream,
                       x, W_ih, W_hh, b_ih, b_hh, se);
    hipLaunchKernelGGL(attn_kernel, dim3(RR * NS / 4), dim3(256), 0, stream,
                       se, nbrs, relnum, w_att, b_att, w_rel, b_rel, rel_rep, rscore);
    hipLaunchKernelGGL(combine_kernel, dim3(NS / 4), dim3(256), 0, stream,
                       se, rel_rep, rscore, w_fc1, b_fc1, out);
}